// Round 7
// baseline (873.701 us; speedup 1.0000x reference)
//
#include <hip/hip_runtime.h>
#include <hip/hip_bf16.h>
#include <math.h>

#define NGRAPHS 256
#define PD_EPS 1e-6f
#define POOL_CHUNK 64
#define NCOLOR 8   // csr-build colors
#define KB 96      // blocks per color; 96 % 8 == 0 so sub determines XCD.
// R6 lesson: color = blockIdx&7 put each color on ONE XCD -> every XCD
// streamed the whole 6.4MB dst through its 4MB L2 (FETCH 59MB, 8x amp).
// color = blockIdx/KB puts the 8 same-sub blocks (identical read stream)
// on the SAME XCD: 1 HBM fetch + 7 L2 hits.

typedef __hip_bfloat16 bf16;
typedef unsigned short ushort_t;
typedef short bf8_t __attribute__((ext_vector_type(8)));   // 8 bf16 = 4 VGPRs
typedef float f4_t __attribute__((ext_vector_type(4)));    // MFMA accumulator

static __device__ __forceinline__ int wave_uniform(int v) {
  return __builtin_amdgcn_readfirstlane(v);
}
static __device__ __forceinline__ float b2f(bf16 h) { return __bfloat162float(h); }
static __device__ __forceinline__ bf16 f2b(float f) { return __float2bfloat16(f); }
static __device__ __forceinline__ short f2bbits(float f) {
  bf16 h = __float2bfloat16(f);
  return *reinterpret_cast<short*>(&h);
}

// ---------- pass1: per-(color,block) partial degree histogram in LDS ----------
__global__ __launch_bounds__(256) void k_count_part(const int* __restrict__ dst,
                                                    ushort_t* __restrict__ partial,
                                                    int E, int n, int rng) {
  extern __shared__ int hist[];
  int color = blockIdx.x / KB;   // see header note: sub -> XCD, color varies in-XCD
  int sub = blockIdx.x % KB;
  int base = color * rng;
  int hi = n - base; if (hi > rng) hi = rng;
  for (int i = threadIdx.x; i < rng; i += 256) hist[i] = 0;
  __syncthreads();
  int e = sub * 256 + threadIdx.x;
  for (; e + 3 * KB * 256 < E; e += 4 * KB * 256) {
    int d0 = dst[e] - base;
    int d1 = dst[e + KB * 256] - base;
    int d2 = dst[e + 2 * KB * 256] - base;
    int d3 = dst[e + 3 * KB * 256] - base;
    if ((unsigned)d0 < (unsigned)hi) atomicAdd(&hist[d0], 1);
    if ((unsigned)d1 < (unsigned)hi) atomicAdd(&hist[d1], 1);
    if ((unsigned)d2 < (unsigned)hi) atomicAdd(&hist[d2], 1);
    if ((unsigned)d3 < (unsigned)hi) atomicAdd(&hist[d3], 1);
  }
  for (; e < E; e += KB * 256) {
    int d = dst[e] - base;
    if ((unsigned)d < (unsigned)hi) atomicAdd(&hist[d], 1);
  }
  __syncthreads();
  ushort_t* outp = partial + (size_t)blockIdx.x * rng;
  for (int i = threadIdx.x; i < rng; i += 256) outp[i] = (ushort_t)hist[i];
}

// ---------- pass2: reduce partials -> cnt + dinv; partials -> exclusive prefix
// over sub-blocks s (block index = c*KB+s, matching the new swizzle) ----------
__global__ void k_reduce_part(ushort_t* __restrict__ partial, int* __restrict__ cnt,
                              float* __restrict__ dinv, int n, int rng) {
  int i = blockIdx.x * 256 + threadIdx.x;
  if (i >= n) return;
  int c = i / rng, li = i - c * rng;
  int acc = 0;
  for (int s = 0; s < KB; ++s) {
    size_t idx = (size_t)(c * KB + s) * rng + li;
    int t = partial[idx];
    partial[idx] = (ushort_t)acc;
    acc += t;
  }
  cnt[i] = acc;
  dinv[i] = 1.0f / sqrtf((float)(acc + 1));  // self-loop => deg >= 1
}

// ---------- 3-phase exclusive scan (N=100k) ----------
__global__ void k_scan1(const int* __restrict__ cnt, int* __restrict__ off,
                        int* __restrict__ bsums, int n) {
  __shared__ int s[256];
  int tid = threadIdx.x;
  int gid = blockIdx.x * 256 + tid;
  int v = (gid < n) ? cnt[gid] : 0;
  s[tid] = v; __syncthreads();
  for (int o = 1; o < 256; o <<= 1) {
    int t = (tid >= o) ? s[tid - o] : 0;
    __syncthreads();
    s[tid] += t;
    __syncthreads();
  }
  if (gid < n) off[gid] = s[tid] - v;
  if (tid == 255) bsums[blockIdx.x] = s[255];
}

__global__ void k_scan2(int* __restrict__ bsums, int nb) {
  __shared__ int s[512];
  int tid = threadIdx.x;
  int v = (tid < nb) ? bsums[tid] : 0;
  s[tid] = v; __syncthreads();
  for (int o = 1; o < 512; o <<= 1) {
    int t = (tid >= o) ? s[tid - o] : 0;
    __syncthreads();
    s[tid] += t;
    __syncthreads();
  }
  if (tid < nb) bsums[tid] = s[tid] - v;
}

__global__ void k_off_final(int* __restrict__ off, const int* __restrict__ bsums,
                            int n, int E) {
  int gid = blockIdx.x * 256 + threadIdx.x;
  if (gid < n) off[gid] += bsums[blockIdx.x];
  if (gid == 0) off[n] = E;
}

// ---------- pass4: colored CSR fill (R4: merged writes; R6: XCD read-share) ----
__global__ __launch_bounds__(256) void k_fill_col(const int* __restrict__ src,
                                                  const int* __restrict__ dst,
                                                  const int* __restrict__ off,
                                                  const ushort_t* __restrict__ partial,
                                                  int* __restrict__ csr, int E, int n,
                                                  int rng) {
  extern __shared__ int cur[];
  int color = blockIdx.x / KB;
  int sub = blockIdx.x % KB;
  int base = color * rng;
  int hi = n - base; if (hi > rng) hi = rng;
  const ushort_t* pp = partial + (size_t)blockIdx.x * rng;
  for (int i = threadIdx.x; i < hi; i += 256) cur[i] = off[base + i] + (int)pp[i];
  __syncthreads();
  for (int e = sub * 256 + threadIdx.x; e < E; e += KB * 256) {
    int d = dst[e] - base;
    if ((unsigned)d < (unsigned)hi) {
      int s = src[e];
      int p = atomicAdd(&cur[d], 1);
      csr[p] = s;
    }
  }
}

// ---------- MFMA GEMM: out[n,f] = dinv[n] * (in[n,:K] @ W[:K,:64]), bf16 out ----
template <int K, int INF32>
__global__ __launch_bounds__(256, 2) void k_gemm_mfma(const void* __restrict__ inv,
                                                      const float* __restrict__ Wg,
                                                      const float* __restrict__ dinv,
                                                      bf16* __restrict__ out, int n) {
  constexpr int KS = K / 32;
  int lane = threadIdx.x & 63;
  int quad = lane >> 4;
  int col = lane & 15;

  bf8_t bfrag[4][KS];
#pragma unroll
  for (int c = 0; c < 4; ++c)
#pragma unroll
    for (int s = 0; s < KS; ++s)
#pragma unroll
      for (int j = 0; j < 8; ++j)
        bfrag[c][s][j] = f2bbits(Wg[(s * 32 + quad * 8 + j) * 64 + c * 16 + col]);

  int wid = (blockIdx.x * blockDim.x + threadIdx.x) >> 6;
  int nw = (gridDim.x * blockDim.x) >> 6;
  int tiles = (n + 15) >> 4;
  for (int t = wid; t < tiles; t += nw) {
    int base = t << 4;
    int arow = base + col;
    if (arow >= n) arow = n - 1;

    bf8_t afrag[KS];
    if (INF32) {
      const float* xr = (const float*)inv + (size_t)arow * K;
#pragma unroll
      for (int s = 0; s < KS; ++s) {
        float4 u0 = *(const float4*)(xr + s * 32 + quad * 8);
        float4 u1 = *(const float4*)(xr + s * 32 + quad * 8 + 4);
        afrag[s][0] = f2bbits(u0.x);
        afrag[s][1] = f2bbits(u0.y);
        afrag[s][2] = f2bbits(u0.z);
        afrag[s][3] = f2bbits(u0.w);
        afrag[s][4] = f2bbits(u1.x);
        afrag[s][5] = f2bbits(u1.y);
        afrag[s][6] = f2bbits(u1.z);
        afrag[s][7] = f2bbits(u1.w);
      }
    } else {
      const bf16* xr = (const bf16*)inv + (size_t)arow * K;
#pragma unroll
      for (int s = 0; s < KS; ++s)
        afrag[s] = *(const bf8_t*)(xr + s * 32 + quad * 8);
    }

    f4_t acc[4];
#pragma unroll
    for (int c = 0; c < 4; ++c) acc[c] = (f4_t){0.f, 0.f, 0.f, 0.f};
#pragma unroll
    for (int s = 0; s < KS; ++s)
#pragma unroll
      for (int c = 0; c < 4; ++c)
        acc[c] = __builtin_amdgcn_mfma_f32_16x16x32_bf16(afrag[s], bfrag[c][s],
                                                         acc[c], 0, 0, 0);
#pragma unroll
    for (int r = 0; r < 4; ++r) {
      int row = base + quad * 4 + r;
      if (row < n) {
        float sc = dinv[row];
#pragma unroll
        for (int c = 0; c < 4; ++c)
          out[(size_t)row * 64 + c * 16 + col] = f2b(acc[c][r] * sc);
      }
    }
  }
}

// ---------- aggregate, 2 nodes per wave over the combined edge range ----------
// out[d] = act(dinv[d]*(sum_{s in N(d)} h'[s] + h'[d]) + b). 16 gathers in
// flight (vs 8 single-node), half the per-node scalar overhead/tail waste.
template <int OUTF32>
__global__ __launch_bounds__(256) void k_agg(const bf16* __restrict__ hp,
                                             const int* __restrict__ off,
                                             const int* __restrict__ csr,
                                             const float* __restrict__ dinv,
                                             const float* __restrict__ bias,
                                             void* __restrict__ outv, int n,
                                             int do_relu) {
  int lane = threadIdx.x & 63;
  int wid = (blockIdx.x * blockDim.x + threadIdx.x) >> 6;
  int nw = (gridDim.x * blockDim.x) >> 6;
  float b = bias[lane];
  int pairs = (n + 1) >> 1;
  for (int pr = wid; pr < pairs; pr += nw) {
    int n0 = wave_uniform(pr << 1);
    int n1 = n0 + 1;
    bool has1 = n1 < n;
    int beg = off[n0];
    int mid = off[n1];
    int end = has1 ? off[n1 + 1] : mid;
    float acc0 = b2f(hp[(size_t)n0 * 64 + lane]);  // self-loops
    float acc1 = has1 ? b2f(hp[(size_t)n1 * 64 + lane]) : 0.f;
    int e = beg;
    for (; e + 16 <= end; e += 16) {
      float a[16];
#pragma unroll
      for (int k = 0; k < 16; ++k) {
        int s = csr[e + k];
        a[k] = b2f(hp[(size_t)s * 64 + lane]);
      }
#pragma unroll
      for (int k = 0; k < 16; ++k) {
        bool c0 = (e + k) < mid;  // wave-uniform select
        acc0 += c0 ? a[k] : 0.f;
        acc1 += c0 ? 0.f : a[k];
      }
    }
    for (; e < end; ++e) {
      int s = csr[e];
      float a = b2f(hp[(size_t)s * 64 + lane]);
      bool c0 = e < mid;
      acc0 += c0 ? a : 0.f;
      acc1 += c0 ? 0.f : a;
    }
    float v0 = fmaf(acc0, dinv[n0], b);
    if (do_relu) v0 = fmaxf(v0, 0.f);
    if (OUTF32)
      ((float*)outv)[(size_t)n0 * 64 + lane] = v0;
    else
      ((bf16*)outv)[(size_t)n0 * 64 + lane] = f2b(v0);
    if (has1) {
      float v1 = fmaf(acc1, dinv[n1], b);
      if (do_relu) v1 = fmaxf(v1, 0.f);
      if (OUTF32)
        ((float*)outv)[(size_t)n1 * 64 + lane] = v1;
      else
        ((bf16*)outv)[(size_t)n1 * 64 + lane] = f2b(v1);
    }
  }
}

// ---------- mean-pool: segment-reduce over sorted batch (R2 fix) ----------
__global__ __launch_bounds__(256) void k_pool(const float* __restrict__ x3,
                                              const int* __restrict__ batch,
                                              float* __restrict__ pooled,
                                              float* __restrict__ cnt, int n) {
  int lane = threadIdx.x & 63;
  int wid = (blockIdx.x * blockDim.x + threadIdx.x) >> 6;
  int beg = wid * POOL_CHUNK;
  if (beg >= n) return;
  int end = beg + POOL_CHUNK;
  if (end > n) end = n;

  int cur = wave_uniform(batch[beg]);
  float acc = 0.f;
  int cl = 0;
  int i = beg;
  for (; i + 4 <= end; i += 4) {
    int g0 = wave_uniform(batch[i + 0]);
    int g3 = wave_uniform(batch[i + 3]);
    float a0 = x3[(size_t)(i + 0) * 64 + lane];
    float a1 = x3[(size_t)(i + 1) * 64 + lane];
    float a2 = x3[(size_t)(i + 2) * 64 + lane];
    float a3 = x3[(size_t)(i + 3) * 64 + lane];
    if (g0 == cur && g3 == cur) {
      acc += a0 + a1 + a2 + a3;
      cl += 4;
    } else {
      float av[4] = {a0, a1, a2, a3};
#pragma unroll
      for (int k = 0; k < 4; ++k) {
        int g = wave_uniform(batch[i + k]);
        if (g != cur) {
          atomicAdd(&pooled[cur * 64 + lane], acc);
          if (lane == 0) atomicAdd(&cnt[cur], (float)cl);
          acc = 0.f; cl = 0; cur = g;
        }
        acc += av[k];
        cl += 1;
      }
    }
  }
  for (; i < end; ++i) {
    int g = wave_uniform(batch[i]);
    float a = x3[(size_t)i * 64 + lane];
    if (g != cur) {
      atomicAdd(&pooled[cur * 64 + lane], acc);
      if (lane == 0) atomicAdd(&cnt[cur], (float)cl);
      acc = 0.f; cl = 0; cur = g;
    }
    acc += a;
    cl += 1;
  }
  atomicAdd(&pooled[cur * 64 + lane], acc);
  if (lane == 0) atomicAdd(&cnt[cur], (float)cl);
}

// ---------- head: both 64x64 GEMMs + L2 distance ----------
__global__ void k_final(const float* __restrict__ pooled1, const float* __restrict__ cnt1,
                        const float* __restrict__ pooled2, const float* __restrict__ cnt2,
                        const float* __restrict__ Wlin, const float* __restrict__ blin,
                        float* __restrict__ outp) {
  int g = blockIdx.x;
  int lane = threadIdx.x;  // 64 threads
  float c1 = fmaxf(cnt1[g], 1.f), c2 = fmaxf(cnt2[g], 1.f);
  float p1 = pooled1[g * 64 + lane] / c1;
  float p2 = pooled2[g * 64 + lane] / c2;
  float e1 = blin[lane], e2 = blin[lane];
  for (int j = 0; j < 64; ++j) {
    float w = Wlin[j * 64 + lane];
    e1 = fmaf(__shfl(p1, j), w, e1);
    e2 = fmaf(__shfl(p2, j), w, e2);
  }
  float d = e1 - e2 + PD_EPS;
  float sq = d * d;
  for (int o = 32; o > 0; o >>= 1) sq += __shfl_down(sq, o);
  if (lane == 0) outp[g] = sqrtf(sq);
}

extern "C" void kernel_launch(void* const* d_in, const int* in_sizes, int n_in,
                              void* d_out, int out_size, void* d_ws, size_t ws_size,
                              hipStream_t stream) {
  const float* x1 = (const float*)d_in[0];
  const int* ei1 = (const int*)d_in[1];
  const int* batch1 = (const int*)d_in[2];
  const float* x2 = (const float*)d_in[3];
  const int* ei2 = (const int*)d_in[4];
  const int* batch2 = (const int*)d_in[5];
  const float* W1 = (const float*)d_in[6];
  const float* b1 = (const float*)d_in[7];
  const float* W2 = (const float*)d_in[8];
  const float* b2 = (const float*)d_in[9];
  const float* W3 = (const float*)d_in[10];
  const float* b3 = (const float*)d_in[11];
  const float* Wlin = (const float*)d_in[12];
  const float* blin = (const float*)d_in[13];

  const int N = in_sizes[2];      // 100000
  const int E = in_sizes[1] / 2;  // 1600000
  const int rng = (N + NCOLOR - 1) / NCOLOR;  // nodes per color (12500)

  // workspace carve (~59 MB); partial (768*12500 ushort = 19.2 MB) aliases
  // bufF (25.6 MB): partial dead after k_fill_col, bufF born at agg3.
  char* p = (char*)d_ws;
  auto alloc = [&](size_t bytes) {
    char* r = p;
    p += (bytes + 255) & ~(size_t)255;
    return r;
  };
  int* off = (int*)alloc((size_t)(N + 1) * 4);
  int* cntn = (int*)alloc((size_t)N * 4);
  int* bsums = (int*)alloc(512 * 4);
  float* dinv = (float*)alloc((size_t)N * 4);
  int* csr = (int*)alloc((size_t)E * 4);
  char* unionbuf = alloc((size_t)N * 64 * 4);  // max(partial 19.2MB, bufF 25.6MB)
  ushort_t* partial = (ushort_t*)unionbuf;
  float* bufF = (float*)unionbuf;
  bf16* hpA = (bf16*)alloc((size_t)N * 64 * 2);
  bf16* hpB = (bf16*)alloc((size_t)N * 64 * 2);
  float* pooled1 = (float*)alloc((size_t)NGRAPHS * 64 * 4);
  float* cnt1 = (float*)alloc((size_t)NGRAPHS * 4);
  float* pooled2 = (float*)alloc((size_t)NGRAPHS * 64 * 4);
  float* cnt2 = (float*)alloc((size_t)NGRAPHS * 4);

  const int nbN = (N + 255) / 256;
  const size_t ldsB = (size_t)rng * 4;  // 50 KB dynamic LDS -> 3 blocks/CU

  for (int t = 0; t < 2; ++t) {
    const float* x = t ? x2 : x1;
    const int* src = t ? ei2 : ei1;
    const int* dst = src + E;
    const int* batch = t ? batch2 : batch1;
    float* pooled = t ? pooled2 : pooled1;
    float* cnt = t ? cnt2 : cnt1;

    hipMemsetAsync(pooled, 0, (size_t)NGRAPHS * 64 * 4, stream);
    hipMemsetAsync(cnt, 0, (size_t)NGRAPHS * 4, stream);

    // CSR build: colored, no device atomics; grid 768 = 3 blocks/CU
    k_count_part<<<NCOLOR * KB, 256, ldsB, stream>>>(dst, partial, E, N, rng);
    k_reduce_part<<<nbN, 256, 0, stream>>>(partial, cntn, dinv, N, rng);
    k_scan1<<<nbN, 256, 0, stream>>>(cntn, off, bsums, N);
    k_scan2<<<1, 512, 0, stream>>>(bsums, nbN);
    k_off_final<<<nbN, 256, 0, stream>>>(off, bsums, N, E);
    k_fill_col<<<NCOLOR * KB, 256, ldsB, stream>>>(src, dst, off, partial, csr, E, N,
                                                   rng);

    // layer 1 (MFMA, f32 input converted in-register)
    k_gemm_mfma<128, 1><<<512, 256, 0, stream>>>(x, W1, dinv, hpA, N);
    k_agg<0><<<2048, 256, 0, stream>>>(hpA, off, csr, dinv, b1, hpB, N, 1);
    // layer 2
    k_gemm_mfma<64, 0><<<512, 256, 0, stream>>>(hpB, W2, dinv, hpA, N);
    k_agg<0><<<2048, 256, 0, stream>>>(hpA, off, csr, dinv, b2, hpB, N, 1);
    // layer 3 (no relu), agg writes f32 for pooling
    k_gemm_mfma<64, 0><<<512, 256, 0, stream>>>(hpB, W3, dinv, hpA, N);
    k_agg<1><<<2048, 256, 0, stream>>>(hpA, off, csr, dinv, b3, bufF, N, 0);

    const int poolWaves = (N + POOL_CHUNK - 1) / POOL_CHUNK;
    k_pool<<<(poolWaves + 3) / 4, 256, 0, stream>>>(bufF, batch, pooled, cnt, N);
  }
  k_final<<<NGRAPHS, 64, 0, stream>>>(pooled1, cnt1, pooled2, cnt2, Wlin, blin,
                                      (float*)d_out);
}

// Round 8
// 709.588 us; speedup vs baseline: 1.2313x; 1.2313x over previous
//
#include <hip/hip_runtime.h>
#include <hip/hip_bf16.h>
#include <math.h>

#define NGRAPHS 256
#define PD_EPS 1e-6f
#define POOL_CHUNK 64
#define NCOLOR 16  // csr-build colors; color = blockIdx & 15 -> color c lives on
                   // XCD c%8 (write-merged csr window, R4/R6 lesson). 16 colors
                   // halve the LDS hist/cursor to 25KB -> 6 blocks/CU (R6 was
                   // 50KB -> 3 blocks/CU -> 28% occupancy, concurrency-bound).
#define CSHIFT 4
#define KB 96      // blocks per color; grid = 1536 = 6/CU = exactly the LDS cap.
// R7 lesson: color = blockIdx/KB shares reads but scatters each csr window's
// writes across all 8 XCDs -> WRITE_SIZE 12 -> 60 MB. Keep color = blockIdx&15.

typedef __hip_bfloat16 bf16;
typedef unsigned short ushort_t;
typedef short bf8_t __attribute__((ext_vector_type(8)));   // 8 bf16 = 4 VGPRs
typedef float f4_t __attribute__((ext_vector_type(4)));    // MFMA accumulator

static __device__ __forceinline__ int wave_uniform(int v) {
  return __builtin_amdgcn_readfirstlane(v);
}
static __device__ __forceinline__ float b2f(bf16 h) { return __bfloat162float(h); }
static __device__ __forceinline__ bf16 f2b(float f) { return __float2bfloat16(f); }
static __device__ __forceinline__ short f2bbits(float f) {
  bf16 h = __float2bfloat16(f);
  return *reinterpret_cast<short*>(&h);
}

// ---------- pass1: per-(color,block) partial degree histogram in LDS ----------
__global__ __launch_bounds__(256) void k_count_part(const int* __restrict__ dst,
                                                    ushort_t* __restrict__ partial,
                                                    int E, int n, int rng) {
  extern __shared__ int hist[];
  int color = blockIdx.x & (NCOLOR - 1);
  int sub = blockIdx.x >> CSHIFT;
  int base = color * rng;
  int hi = n - base; if (hi > rng) hi = rng;
  for (int i = threadIdx.x; i < rng; i += 256) hist[i] = 0;
  __syncthreads();
  int e = sub * 256 + threadIdx.x;
  for (; e + 3 * KB * 256 < E; e += 4 * KB * 256) {
    int d0 = dst[e] - base;
    int d1 = dst[e + KB * 256] - base;
    int d2 = dst[e + 2 * KB * 256] - base;
    int d3 = dst[e + 3 * KB * 256] - base;
    if ((unsigned)d0 < (unsigned)hi) atomicAdd(&hist[d0], 1);
    if ((unsigned)d1 < (unsigned)hi) atomicAdd(&hist[d1], 1);
    if ((unsigned)d2 < (unsigned)hi) atomicAdd(&hist[d2], 1);
    if ((unsigned)d3 < (unsigned)hi) atomicAdd(&hist[d3], 1);
  }
  for (; e < E; e += KB * 256) {
    int d = dst[e] - base;
    if ((unsigned)d < (unsigned)hi) atomicAdd(&hist[d], 1);
  }
  __syncthreads();
  ushort_t* outp = partial + (size_t)blockIdx.x * rng;
  for (int i = threadIdx.x; i < rng; i += 256) outp[i] = (ushort_t)hist[i];
}

// ---------- pass2: reduce partials -> cnt + dinv; partials -> exclusive prefix
// over sub-blocks (block index = s*NCOLOR + c, matching the swizzle) ----------
__global__ void k_reduce_part(ushort_t* __restrict__ partial, int* __restrict__ cnt,
                              float* __restrict__ dinv, int n, int rng) {
  int i = blockIdx.x * 256 + threadIdx.x;
  if (i >= n) return;
  int c = i / rng, li = i - c * rng;
  int acc = 0;
  for (int s = 0; s < KB; ++s) {
    size_t idx = (size_t)(s * NCOLOR + c) * rng + li;
    int t = partial[idx];
    partial[idx] = (ushort_t)acc;
    acc += t;
  }
  cnt[i] = acc;
  dinv[i] = 1.0f / sqrtf((float)(acc + 1));  // self-loop => deg >= 1
}

// ---------- 3-phase exclusive scan (N=100k) ----------
__global__ void k_scan1(const int* __restrict__ cnt, int* __restrict__ off,
                        int* __restrict__ bsums, int n) {
  __shared__ int s[256];
  int tid = threadIdx.x;
  int gid = blockIdx.x * 256 + tid;
  int v = (gid < n) ? cnt[gid] : 0;
  s[tid] = v; __syncthreads();
  for (int o = 1; o < 256; o <<= 1) {
    int t = (tid >= o) ? s[tid - o] : 0;
    __syncthreads();
    s[tid] += t;
    __syncthreads();
  }
  if (gid < n) off[gid] = s[tid] - v;
  if (tid == 255) bsums[blockIdx.x] = s[255];
}

__global__ void k_scan2(int* __restrict__ bsums, int nb) {
  __shared__ int s[512];
  int tid = threadIdx.x;
  int v = (tid < nb) ? bsums[tid] : 0;
  s[tid] = v; __syncthreads();
  for (int o = 1; o < 512; o <<= 1) {
    int t = (tid >= o) ? s[tid - o] : 0;
    __syncthreads();
    s[tid] += t;
    __syncthreads();
  }
  if (tid < nb) bsums[tid] = s[tid] - v;
}

__global__ void k_off_final(int* __restrict__ off, const int* __restrict__ bsums,
                            int n, int E) {
  int gid = blockIdx.x * 256 + threadIdx.x;
  if (gid < n) off[gid] += bsums[blockIdx.x];
  if (gid == 0) off[n] = E;
}

// ---------- pass4: colored CSR fill (R4: merged writes; R8: 25KB cursors) ----
__global__ __launch_bounds__(256) void k_fill_col(const int* __restrict__ src,
                                                  const int* __restrict__ dst,
                                                  const int* __restrict__ off,
                                                  const ushort_t* __restrict__ partial,
                                                  int* __restrict__ csr, int E, int n,
                                                  int rng) {
  extern __shared__ int cur[];
  int color = blockIdx.x & (NCOLOR - 1);
  int sub = blockIdx.x >> CSHIFT;
  int base = color * rng;
  int hi = n - base; if (hi > rng) hi = rng;
  const ushort_t* pp = partial + (size_t)blockIdx.x * rng;
  for (int i = threadIdx.x; i < hi; i += 256) cur[i] = off[base + i] + (int)pp[i];
  __syncthreads();
  for (int e = sub * 256 + threadIdx.x; e < E; e += KB * 256) {
    int d = dst[e] - base;
    if ((unsigned)d < (unsigned)hi) {
      int s = src[e];
      int p = atomicAdd(&cur[d], 1);
      csr[p] = s;
    }
  }
}

// ---------- MFMA GEMM: out[n,f] = dinv[n] * (in[n,:K] @ W[:K,:64]), bf16 out ----
template <int K, int INF32>
__global__ __launch_bounds__(256, 2) void k_gemm_mfma(const void* __restrict__ inv,
                                                      const float* __restrict__ Wg,
                                                      const float* __restrict__ dinv,
                                                      bf16* __restrict__ out, int n) {
  constexpr int KS = K / 32;
  int lane = threadIdx.x & 63;
  int quad = lane >> 4;
  int col = lane & 15;

  bf8_t bfrag[4][KS];
#pragma unroll
  for (int c = 0; c < 4; ++c)
#pragma unroll
    for (int s = 0; s < KS; ++s)
#pragma unroll
      for (int j = 0; j < 8; ++j)
        bfrag[c][s][j] = f2bbits(Wg[(s * 32 + quad * 8 + j) * 64 + c * 16 + col]);

  int wid = (blockIdx.x * blockDim.x + threadIdx.x) >> 6;
  int nw = (gridDim.x * blockDim.x) >> 6;
  int tiles = (n + 15) >> 4;
  for (int t = wid; t < tiles; t += nw) {
    int base = t << 4;
    int arow = base + col;
    if (arow >= n) arow = n - 1;

    bf8_t afrag[KS];
    if (INF32) {
      const float* xr = (const float*)inv + (size_t)arow * K;
#pragma unroll
      for (int s = 0; s < KS; ++s) {
        float4 u0 = *(const float4*)(xr + s * 32 + quad * 8);
        float4 u1 = *(const float4*)(xr + s * 32 + quad * 8 + 4);
        afrag[s][0] = f2bbits(u0.x);
        afrag[s][1] = f2bbits(u0.y);
        afrag[s][2] = f2bbits(u0.z);
        afrag[s][3] = f2bbits(u0.w);
        afrag[s][4] = f2bbits(u1.x);
        afrag[s][5] = f2bbits(u1.y);
        afrag[s][6] = f2bbits(u1.z);
        afrag[s][7] = f2bbits(u1.w);
      }
    } else {
      const bf16* xr = (const bf16*)inv + (size_t)arow * K;
#pragma unroll
      for (int s = 0; s < KS; ++s)
        afrag[s] = *(const bf8_t*)(xr + s * 32 + quad * 8);
    }

    f4_t acc[4];
#pragma unroll
    for (int c = 0; c < 4; ++c) acc[c] = (f4_t){0.f, 0.f, 0.f, 0.f};
#pragma unroll
    for (int s = 0; s < KS; ++s)
#pragma unroll
      for (int c = 0; c < 4; ++c)
        acc[c] = __builtin_amdgcn_mfma_f32_16x16x32_bf16(afrag[s], bfrag[c][s],
                                                         acc[c], 0, 0, 0);
#pragma unroll
    for (int r = 0; r < 4; ++r) {
      int row = base + quad * 4 + r;
      if (row < n) {
        float sc = dinv[row];
#pragma unroll
        for (int c = 0; c < 4; ++c)
          out[(size_t)row * 64 + c * 16 + col] = f2b(acc[c][r] * sc);
      }
    }
  }
}

// ---------- aggregate (R6 form: single node/wave, 8 gathers in flight) ----------
// R7's 2-node pairing regressed ~25us/dispatch: cndmask select doubled the
// VALU work per gathered element and halved wave-level parallelism. Reverted.
template <int OUTF32>
__global__ __launch_bounds__(256) void k_agg(const bf16* __restrict__ hp,
                                             const int* __restrict__ off,
                                             const int* __restrict__ csr,
                                             const float* __restrict__ dinv,
                                             const float* __restrict__ bias,
                                             void* __restrict__ outv, int n,
                                             int do_relu) {
  int lane = threadIdx.x & 63;
  int wid = (blockIdx.x * blockDim.x + threadIdx.x) >> 6;
  int nw = (gridDim.x * blockDim.x) >> 6;
  float b = bias[lane];
  for (int node = wid; node < n; node += nw) {
    int un = wave_uniform(node);
    int beg = off[un], end = off[un + 1];
    float acc = b2f(hp[(size_t)un * 64 + lane]);  // self-loop
    int e = beg;
    for (; e + 8 <= end; e += 8) {
      int s0 = csr[e + 0], s1 = csr[e + 1], s2 = csr[e + 2], s3 = csr[e + 3];
      int s4 = csr[e + 4], s5 = csr[e + 5], s6 = csr[e + 6], s7 = csr[e + 7];
      float a0 = b2f(hp[(size_t)s0 * 64 + lane]);
      float a1 = b2f(hp[(size_t)s1 * 64 + lane]);
      float a2 = b2f(hp[(size_t)s2 * 64 + lane]);
      float a3 = b2f(hp[(size_t)s3 * 64 + lane]);
      float a4 = b2f(hp[(size_t)s4 * 64 + lane]);
      float a5 = b2f(hp[(size_t)s5 * 64 + lane]);
      float a6 = b2f(hp[(size_t)s6 * 64 + lane]);
      float a7 = b2f(hp[(size_t)s7 * 64 + lane]);
      acc += ((a0 + a1) + (a2 + a3)) + ((a4 + a5) + (a6 + a7));
    }
    for (; e < end; ++e) acc += b2f(hp[(size_t)csr[e] * 64 + lane]);
    float v = fmaf(acc, dinv[un], b);
    if (do_relu) v = fmaxf(v, 0.f);
    if (OUTF32)
      ((float*)outv)[(size_t)un * 64 + lane] = v;
    else
      ((bf16*)outv)[(size_t)un * 64 + lane] = f2b(v);
  }
}

// ---------- mean-pool: segment-reduce over sorted batch (R2 fix) ----------
__global__ __launch_bounds__(256) void k_pool(const float* __restrict__ x3,
                                              const int* __restrict__ batch,
                                              float* __restrict__ pooled,
                                              float* __restrict__ cnt, int n) {
  int lane = threadIdx.x & 63;
  int wid = (blockIdx.x * blockDim.x + threadIdx.x) >> 6;
  int beg = wid * POOL_CHUNK;
  if (beg >= n) return;
  int end = beg + POOL_CHUNK;
  if (end > n) end = n;

  int cur = wave_uniform(batch[beg]);
  float acc = 0.f;
  int cl = 0;
  int i = beg;
  for (; i + 4 <= end; i += 4) {
    int g0 = wave_uniform(batch[i + 0]);
    int g3 = wave_uniform(batch[i + 3]);
    float a0 = x3[(size_t)(i + 0) * 64 + lane];
    float a1 = x3[(size_t)(i + 1) * 64 + lane];
    float a2 = x3[(size_t)(i + 2) * 64 + lane];
    float a3 = x3[(size_t)(i + 3) * 64 + lane];
    if (g0 == cur && g3 == cur) {
      acc += a0 + a1 + a2 + a3;
      cl += 4;
    } else {
      float av[4] = {a0, a1, a2, a3};
#pragma unroll
      for (int k = 0; k < 4; ++k) {
        int g = wave_uniform(batch[i + k]);
        if (g != cur) {
          atomicAdd(&pooled[cur * 64 + lane], acc);
          if (lane == 0) atomicAdd(&cnt[cur], (float)cl);
          acc = 0.f; cl = 0; cur = g;
        }
        acc += av[k];
        cl += 1;
      }
    }
  }
  for (; i < end; ++i) {
    int g = wave_uniform(batch[i]);
    float a = x3[(size_t)i * 64 + lane];
    if (g != cur) {
      atomicAdd(&pooled[cur * 64 + lane], acc);
      if (lane == 0) atomicAdd(&cnt[cur], (float)cl);
      acc = 0.f; cl = 0; cur = g;
    }
    acc += a;
    cl += 1;
  }
  atomicAdd(&pooled[cur * 64 + lane], acc);
  if (lane == 0) atomicAdd(&cnt[cur], (float)cl);
}

// ---------- head: both 64x64 GEMMs + L2 distance ----------
__global__ void k_final(const float* __restrict__ pooled1, const float* __restrict__ cnt1,
                        const float* __restrict__ pooled2, const float* __restrict__ cnt2,
                        const float* __restrict__ Wlin, const float* __restrict__ blin,
                        float* __restrict__ outp) {
  int g = blockIdx.x;
  int lane = threadIdx.x;  // 64 threads
  float c1 = fmaxf(cnt1[g], 1.f), c2 = fmaxf(cnt2[g], 1.f);
  float p1 = pooled1[g * 64 + lane] / c1;
  float p2 = pooled2[g * 64 + lane] / c2;
  float e1 = blin[lane], e2 = blin[lane];
  for (int j = 0; j < 64; ++j) {
    float w = Wlin[j * 64 + lane];
    e1 = fmaf(__shfl(p1, j), w, e1);
    e2 = fmaf(__shfl(p2, j), w, e2);
  }
  float d = e1 - e2 + PD_EPS;
  float sq = d * d;
  for (int o = 32; o > 0; o >>= 1) sq += __shfl_down(sq, o);
  if (lane == 0) outp[g] = sqrtf(sq);
}

extern "C" void kernel_launch(void* const* d_in, const int* in_sizes, int n_in,
                              void* d_out, int out_size, void* d_ws, size_t ws_size,
                              hipStream_t stream) {
  const float* x1 = (const float*)d_in[0];
  const int* ei1 = (const int*)d_in[1];
  const int* batch1 = (const int*)d_in[2];
  const float* x2 = (const float*)d_in[3];
  const int* ei2 = (const int*)d_in[4];
  const int* batch2 = (const int*)d_in[5];
  const float* W1 = (const float*)d_in[6];
  const float* b1 = (const float*)d_in[7];
  const float* W2 = (const float*)d_in[8];
  const float* b2 = (const float*)d_in[9];
  const float* W3 = (const float*)d_in[10];
  const float* b3 = (const float*)d_in[11];
  const float* Wlin = (const float*)d_in[12];
  const float* blin = (const float*)d_in[13];

  const int N = in_sizes[2];      // 100000
  const int E = in_sizes[1] / 2;  // 1600000
  const int rng = (N + NCOLOR - 1) / NCOLOR;  // nodes per color (6250)

  // workspace carve (~59 MB); partial (1536*6250 ushort = 19.2 MB) aliases
  // bufF (25.6 MB): partial dead after k_fill_col, bufF born at agg3.
  char* p = (char*)d_ws;
  auto alloc = [&](size_t bytes) {
    char* r = p;
    p += (bytes + 255) & ~(size_t)255;
    return r;
  };
  int* off = (int*)alloc((size_t)(N + 1) * 4);
  int* cntn = (int*)alloc((size_t)N * 4);
  int* bsums = (int*)alloc(512 * 4);
  float* dinv = (float*)alloc((size_t)N * 4);
  int* csr = (int*)alloc((size_t)E * 4);
  char* unionbuf = alloc((size_t)N * 64 * 4);  // max(partial 19.2MB, bufF 25.6MB)
  ushort_t* partial = (ushort_t*)unionbuf;
  float* bufF = (float*)unionbuf;
  bf16* hpA = (bf16*)alloc((size_t)N * 64 * 2);
  bf16* hpB = (bf16*)alloc((size_t)N * 64 * 2);
  float* pooled1 = (float*)alloc((size_t)NGRAPHS * 64 * 4);
  float* cnt1 = (float*)alloc((size_t)NGRAPHS * 4);
  float* pooled2 = (float*)alloc((size_t)NGRAPHS * 64 * 4);
  float* cnt2 = (float*)alloc((size_t)NGRAPHS * 4);

  const int nbN = (N + 255) / 256;
  const size_t ldsB = (size_t)rng * 4;  // 25 KB dynamic LDS -> 6 blocks/CU

  for (int t = 0; t < 2; ++t) {
    const float* x = t ? x2 : x1;
    const int* src = t ? ei2 : ei1;
    const int* dst = src + E;
    const int* batch = t ? batch2 : batch1;
    float* pooled = t ? pooled2 : pooled1;
    float* cnt = t ? cnt2 : cnt1;

    hipMemsetAsync(pooled, 0, (size_t)NGRAPHS * 64 * 4, stream);
    hipMemsetAsync(cnt, 0, (size_t)NGRAPHS * 4, stream);

    // CSR build: colored, no device atomics; grid 1536 = 6 blocks/CU
    k_count_part<<<NCOLOR * KB, 256, ldsB, stream>>>(dst, partial, E, N, rng);
    k_reduce_part<<<nbN, 256, 0, stream>>>(partial, cntn, dinv, N, rng);
    k_scan1<<<nbN, 256, 0, stream>>>(cntn, off, bsums, N);
    k_scan2<<<1, 512, 0, stream>>>(bsums, nbN);
    k_off_final<<<nbN, 256, 0, stream>>>(off, bsums, N, E);
    k_fill_col<<<NCOLOR * KB, 256, ldsB, stream>>>(src, dst, off, partial, csr, E, N,
                                                   rng);

    // layer 1 (MFMA, f32 input converted in-register)
    k_gemm_mfma<128, 1><<<512, 256, 0, stream>>>(x, W1, dinv, hpA, N);
    k_agg<0><<<2048, 256, 0, stream>>>(hpA, off, csr, dinv, b1, hpB, N, 1);
    // layer 2
    k_gemm_mfma<64, 0><<<512, 256, 0, stream>>>(hpB, W2, dinv, hpA, N);
    k_agg<0><<<2048, 256, 0, stream>>>(hpA, off, csr, dinv, b2, hpB, N, 1);
    // layer 3 (no relu), agg writes f32 for pooling
    k_gemm_mfma<64, 0><<<512, 256, 0, stream>>>(hpB, W3, dinv, hpA, N);
    k_agg<1><<<2048, 256, 0, stream>>>(hpA, off, csr, dinv, b3, bufF, N, 0);

    const int poolWaves = (N + POOL_CHUNK - 1) / POOL_CHUNK;
    k_pool<<<(poolWaves + 3) / 4, 256, 0, stream>>>(bufF, batch, pooled, cnt, N);
  }
  k_final<<<NGRAPHS, 64, 0, stream>>>(pooled1, cnt1, pooled2, cnt2, Wlin, blin,
                                      (float*)d_out);
}